// Round 15
// baseline (334.006 us; speedup 1.0000x reference)
//
#include <hip/hip_runtime.h>

// Problem constants (B=2, L=2048, H=1024, NH=16, HD=64)
#define NBATCH 2
#define LSEQ   2048
#define NH     16
#define HD     64
#define HDIM   1024
#define MTOK   4096   // NBATCH * LSEQ

typedef unsigned short u16;
typedef __attribute__((ext_vector_type(8))) short bf16x8;  // 8 bf16 (4 VGPRs)
typedef __attribute__((ext_vector_type(4))) float f32x4;

__device__ __forceinline__ u16 f2bf(float f) {
  union { float f; unsigned int u; } x; x.f = f;
  return (u16)((x.u + 0x7fffu + ((x.u >> 16) & 1u)) >> 16);  // RNE
}

__device__ __forceinline__ void gload_lds16(const void* g, void* l) {
  __builtin_amdgcn_global_load_lds(
      (const __attribute__((address_space(1))) unsigned int*)g,
      (__attribute__((address_space(3))) unsigned int*)l, 16, 0, 0);
}

// ---------------- prep: fp32->bf16 converts (z=0..2) + weight transposes (z=3) ----
__global__ void prep_kernel(
    const float* __restrict__ q, const float* __restrict__ k, const float* __restrict__ v,
    const float* __restrict__ W0, const float* __restrict__ W1,
    const float* __restrict__ W2, const float* __restrict__ W3,
    u16* __restrict__ xq, u16* __restrict__ xk, u16* __restrict__ xv,
    u16* __restrict__ T0, u16* __restrict__ T1, u16* __restrict__ T2,
    u16* __restrict__ T3) {
  __shared__ float tile[64][65];
  if (blockIdx.z < 3) {
    const float* in = (blockIdx.z == 0) ? q : (blockIdx.z == 1) ? k : v;
    u16* out = (blockIdx.z == 0) ? xq : (blockIdx.z == 1) ? xk : xv;
    int i = blockIdx.x * blockDim.x + threadIdx.x;  // 4096 blocks cover n/4
    float4 t4 = ((const float4*)in)[i];
    ushort4 o;
    o.x = f2bf(t4.x); o.y = f2bf(t4.y); o.z = f2bf(t4.z); o.w = f2bf(t4.w);
    ((ushort4*)out)[i] = o;
    return;
  }
  // z == 3: weight transpose+convert, 256 blocks per weight
  if (blockIdx.x >= 1024) return;
  const int sel = blockIdx.x >> 8, bx = blockIdx.x & 255;
  const float* W = (sel == 0) ? W0 : (sel == 1) ? W1 : (sel == 2) ? W2 : W3;
  u16* Wt = (sel == 0) ? T0 : (sel == 1) ? T1 : (sel == 2) ? T2 : T3;
  const int k0 = (bx & 15) << 6;
  const int n0 = (bx >> 4) << 6;
  const int t = threadIdx.x;
#pragma unroll
  for (int i = 0; i < 4; ++i) {
    int idx = t + i * 256;
    int r = idx >> 4, c = (idx & 15) << 2;
    float4 v4 = *(const float4*)&W[(size_t)(k0 + r) * HDIM + n0 + c];
    tile[r][c] = v4.x; tile[r][c + 1] = v4.y; tile[r][c + 2] = v4.z; tile[r][c + 3] = v4.w;
  }
  __syncthreads();
#pragma unroll
  for (int i = 0; i < 4; ++i) {
    int idx = t + i * 256;
    int r = idx >> 4, c = (idx & 15) << 2;  // r = n-local, c = k-local
    ushort4 o;
    o.x = f2bf(tile[c][r]);     o.y = f2bf(tile[c + 1][r]);
    o.z = f2bf(tile[c + 2][r]); o.w = f2bf(tile[c + 3][r]);
    *(ushort4*)&Wt[(size_t)(n0 + r) * HDIM + k0 + c] = o;
  }
}

// ---------------- GEMM core (proj): C[M,N] = A[M,K] * Bt[N,K]^T + bias --------
// 128x128 tile, BK=64, 4 waves (2x2), 16x16x32 bf16 MFMA. m97-style structure.
// MODE 0: write bf16 head-major Qh/Kh [B][NH][L][HD]
// MODE 2: write bf16 transposed Vt [B][NH][HD][L]
template <int MODE>
__device__ __forceinline__ void gemm_core(u16* As, u16* Bs, int m0, int n0,
    const u16* __restrict__ A, const u16* __restrict__ Bt,
    const float* __restrict__ bias, void* __restrict__ Cout) {
  const int tid = threadIdx.x;
  const int lane = tid & 63, wid = tid >> 6;
  const int l15 = lane & 15, g = lane >> 4;
  const int wr = wid >> 1, wc = wid & 1;
  f32x4 acc[4][4];
#pragma unroll
  for (int i = 0; i < 4; ++i)
#pragma unroll
    for (int j = 0; j < 4; ++j) acc[i][j] = (f32x4){0.f, 0.f, 0.f, 0.f};

  for (int t = 0; t < HDIM / 64; ++t) {
    const int k0 = t * 64;
    __syncthreads();  // previous tile fully consumed
#pragma unroll
    for (int i = 0; i < 4; ++i) {
      const int row = wid * 32 + i * 8 + (lane >> 3);
      const int colb = (lane & 7) * 16;
      gload_lds16((const char*)(A + (size_t)(m0 + row) * HDIM + k0) + colb,
                  (char*)As + (wid * 32 + i * 8) * 128);
      gload_lds16((const char*)(Bt + (size_t)(n0 + row) * HDIM + k0) + colb,
                  (char*)Bs + (wid * 32 + i * 8) * 128);
    }
    __syncthreads();  // staging visible (drains vmcnt)
#pragma unroll
    for (int ks = 0; ks < 2; ++ks) {
      bf16x8 a[4], b[4];
#pragma unroll
      for (int i = 0; i < 4; ++i) {
        const int row = wr * 64 + i * 16 + l15;
        a[i] = *(const bf16x8*)((const char*)As + row * 128 + ks * 64 + g * 16);
      }
#pragma unroll
      for (int j = 0; j < 4; ++j) {
        const int row = wc * 64 + j * 16 + l15;
        b[j] = *(const bf16x8*)((const char*)Bs + row * 128 + ks * 64 + g * 16);
      }
#pragma unroll
      for (int i = 0; i < 4; ++i)
#pragma unroll
        for (int j = 0; j < 4; ++j)
          acc[i][j] = __builtin_amdgcn_mfma_f32_16x16x32_bf16(a[i], b[j], acc[i][j], 0, 0, 0);
    }
  }
  // epilogue: C row = m0 + wr*64 + i*16 + 4*g + r ; col = n0 + wc*64 + j*16 + l15
#pragma unroll
  for (int i = 0; i < 4; ++i) {
    const int mrow = m0 + wr * 64 + i * 16 + 4 * g;
#pragma unroll
    for (int j = 0; j < 4; ++j) {
      const int ncol = n0 + wc * 64 + j * 16 + l15;
      const float bb = bias[ncol];
      if (MODE == 2) {
        const int bidx = mrow >> 11, l0 = mrow & (LSEQ - 1);
        const int h = ncol >> 6, d = ncol & 63;
        ushort4 o4;
        o4.x = f2bf(acc[i][j][0] + bb); o4.y = f2bf(acc[i][j][1] + bb);
        o4.z = f2bf(acc[i][j][2] + bb); o4.w = f2bf(acc[i][j][3] + bb);
        *(ushort4*)&((u16*)Cout)[(((size_t)bidx * NH + h) * HD + d) * LSEQ + l0] = o4;
      } else {
        const int h = ncol >> 6, d = ncol & 63;
        u16* o = (u16*)Cout;
#pragma unroll
        for (int r = 0; r < 4; ++r) {
          const int m = mrow + r;
          const int bidx = m >> 11, l = m & (LSEQ - 1);
          o[(((size_t)bidx * NH + h) * LSEQ + l) * HD + d] = f2bf(acc[i][j][r] + bb);
        }
      }
    }
  }
}

// proj: 1-D grid 768, XCD-bijective swizzle (nwg%8==0)
__global__ __launch_bounds__(256, 3) void proj_gemm_kernel(
    const u16* __restrict__ xq, const u16* __restrict__ xk, const u16* __restrict__ xv,
    const u16* __restrict__ WqT, const u16* __restrict__ WkT, const u16* __restrict__ WvT,
    const float* __restrict__ bq, const float* __restrict__ bk, const float* __restrict__ bv,
    u16* __restrict__ Qh, u16* __restrict__ Kh, u16* __restrict__ Vt) {
  __shared__ u16 As[128 * 64];
  __shared__ u16 Bs[128 * 64];
  const int h = blockIdx.x;
  const int l = (h & 7) * 96 + (h >> 3);  // XCD h&7 gets 96 consecutive tiles
  const int z = l >> 8, rem = l & 255;
  const int m0 = (rem >> 3) * 128, n0 = (rem & 7) * 128;
  if (z == 0)      gemm_core<0>(As, Bs, m0, n0, xq, WqT, bq, Qh);
  else if (z == 1) gemm_core<0>(As, Bs, m0, n0, xk, WkT, bk, Kh);
  else             gemm_core<2>(As, Bs, m0, n0, xv, WvT, bv, Vt);
}

// out: 128x64 tile, 512 blocks = 2/CU. 4 waves 2x2: wr rows 64, wc cols 32.
__global__ __launch_bounds__(256, 2) void out_gemm_kernel(
    const u16* __restrict__ A, const u16* __restrict__ WoT,
    const float* __restrict__ bo, float* __restrict__ out) {
  __shared__ u16 As[128 * 64];  // 16 KB
  __shared__ u16 Bs[64 * 64];   // 8 KB
  const int h = blockIdx.x;
  const int l = (h & 7) * 64 + (h >> 3);  // XCD-bijective (512 % 8 == 0)
  const int m0 = (l >> 4) * 128, n0 = (l & 15) * 64;
  const int lane = threadIdx.x & 63, wid = threadIdx.x >> 6;
  const int l15 = lane & 15, g = lane >> 4;
  const int wr = wid >> 1, wc = wid & 1;
  f32x4 acc[4][2];
#pragma unroll
  for (int i = 0; i < 4; ++i)
#pragma unroll
    for (int j = 0; j < 2; ++j) acc[i][j] = (f32x4){0.f, 0.f, 0.f, 0.f};

  for (int t = 0; t < HDIM / 64; ++t) {
    const int k0 = t * 64;
    __syncthreads();
    const int colb = (lane & 7) * 16;
#pragma unroll
    for (int i = 0; i < 4; ++i) {  // A: 32 rows per wave (128 total)
      const int row = wid * 32 + i * 8 + (lane >> 3);
      gload_lds16((const char*)(A + (size_t)(m0 + row) * HDIM + k0) + colb,
                  (char*)As + (wid * 32 + i * 8) * 128);
    }
#pragma unroll
    for (int i = 0; i < 2; ++i) {  // B: 16 rows per wave (64 total)
      const int row = wid * 16 + i * 8 + (lane >> 3);
      gload_lds16((const char*)(WoT + (size_t)(n0 + row) * HDIM + k0) + colb,
                  (char*)Bs + (wid * 16 + i * 8) * 128);
    }
    __syncthreads();
#pragma unroll
    for (int ks = 0; ks < 2; ++ks) {
      bf16x8 a[4], b[2];
#pragma unroll
      for (int i = 0; i < 4; ++i) {
        const int row = wr * 64 + i * 16 + l15;
        a[i] = *(const bf16x8*)((const char*)As + row * 128 + ks * 64 + g * 16);
      }
#pragma unroll
      for (int j = 0; j < 2; ++j) {
        const int row = wc * 32 + j * 16 + l15;
        b[j] = *(const bf16x8*)((const char*)Bs + row * 128 + ks * 64 + g * 16);
      }
#pragma unroll
      for (int i = 0; i < 4; ++i)
#pragma unroll
        for (int j = 0; j < 2; ++j)
          acc[i][j] = __builtin_amdgcn_mfma_f32_16x16x32_bf16(a[i], b[j], acc[i][j], 0, 0, 0);
    }
  }
#pragma unroll
  for (int i = 0; i < 4; ++i) {
    const int mrow = m0 + wr * 64 + i * 16 + 4 * g;
#pragma unroll
    for (int j = 0; j < 2; ++j) {
      const int ncol = n0 + wc * 32 + j * 16 + l15;
      const float bb = bo[ncol];
#pragma unroll
      for (int r = 0; r < 4; ++r)
        out[(size_t)(mrow + r) * HDIM + ncol] = acc[i][j][r] + bb;
    }
  }
}

// ---------------- flash attention (R12-best: QBLK=128, double-buffer, vmcnt(4)) ----
// 512 blocks x 512 threads (8 waves), each wave owns 16 q-rows. K/V tiles of 64
// double-buffered; each wave stages one 8-row slab of K and V (2 gload_lds/tile).
// bh-local XCD swizzle. Mask prefetched two tiles ahead in registers (mvA/mvB);
// end-of-tile barrier waits vmcnt(4) so mask loads stay in flight.
__global__ __launch_bounds__(512, 4) void attn_kernel(
    const u16* __restrict__ Qh, const u16* __restrict__ Kh,
    const u16* __restrict__ Vt, const float* __restrict__ mask,
    u16* __restrict__ Out /* [B][L][NH][HD] bf16 */) {
  __shared__ u16 Ks[2][64 * 64];   // 16 KB
  __shared__ u16 Vs[2][64 * 64];   // 16 KB
  __shared__ u16 Ps[8][16 * 64];   // 16 KB
  const int lane = threadIdx.x & 63, w = threadIdx.x >> 6;  // w in 0..7
  const int l15 = lane & 15, g = lane >> 4;
  // bh-locality swizzle: 512 blocks = 8 XCD x (4 heads x 16 q-blocks)
  const int kk = blockIdx.x >> 3, xcd = blockIdx.x & 7;
  const int bh = xcd * 4 + (kk >> 4);
  const int qb = kk & 15;
  const int q0 = qb * 128 + w * 16;
  const int NT = LSEQ / 64;

  // Q fragments: lane holds Q[q0 + l15][ks*32 + g*8 + j]
  bf16x8 aq[2];
  {
    const u16* qbase = Qh + ((size_t)bh * LSEQ + q0 + l15) * HD;
    aq[0] = *(const bf16x8*)(qbase + g * 8);
    aq[1] = *(const bf16x8*)(qbase + 32 + g * 8);
  }
  f32x4 o_acc[4];
#pragma unroll
  for (int db = 0; db < 4; ++db) o_acc[db] = (f32x4){0.f, 0.f, 0.f, 0.f};
  float m_run = -1e30f, l_run = 0.f;  // this lane's q-row = q0 + l15

  const size_t kbase = (size_t)bh * LSEQ * HD;   // Kh[bh][l][d]
  const size_t vbase = (size_t)bh * HD * LSEQ;   // Vt[bh][d][l]
  const int srow = w * 8 + (lane >> 3);          // this wave's staging row
  const int scolb = (lane & 7) * 16;

#define STAGE(buf, tt) do {                                                    \
    const int kv0_ = (tt) * 64;                                                \
    const int cb_ = scolb ^ ((srow & 7) << 4);                                 \
    gload_lds16((const char*)(Kh + kbase + (size_t)(kv0_ + srow) * HD) + cb_,  \
                (char*)Ks[buf] + (w * 8) * 128);                               \
    gload_lds16((const char*)(Vt + vbase + (size_t)srow * LSEQ + kv0_) + cb_,  \
                (char*)Vs[buf] + (w * 8) * 128);                               \
  } while (0)

  const float* mrow = mask + ((size_t)bh * LSEQ + q0 + l15) * LSEQ;
  f32x4 mvA[4], mvB[4];

  STAGE(0, 0);
#pragma unroll
  for (int mb = 0; mb < 4; ++mb) {  // mask tiles 0 and 1
    mvA[mb] = *(const f32x4*)(mrow + 0 * 64 + mb * 16 + 4 * g);
    mvB[mb] = *(const f32x4*)(mrow + 1 * 64 + mb * 16 + 4 * g);
  }
  __syncthreads();  // one-time full drain: tile 0 staged

  u16* pbase = Ps[w];
  const int srcbase = (lane & 48) | ((lane & 48) >> 2);  // lane g*16 + 4g (+r)
  const int pswz = (l15 & 7) << 4;

  // ---- one tile body; mv = this tile's mask regs (reloaded for t+2) ----
#define TILE_BODY(t, cur, mv) do {                                            \
    if ((t) + 1 < NT) STAGE((cur) ^ 1, (t) + 1);                              \
    /* S^T via mfma(K,Q): s_acc[mb][r] = S[q=l15][kv=mb*16+4g+r] */           \
    f32x4 s_acc[4];                                                           \
    _Pragma("unroll")                                                         \
    for (int mb = 0; mb < 4; ++mb) s_acc[mb] = (f32x4){0.f, 0.f, 0.f, 0.f};   \
    __builtin_amdgcn_s_setprio(1);                                            \
    _Pragma("unroll")                                                         \
    for (int ks = 0; ks < 2; ++ks) {                                          \
      _Pragma("unroll")                                                       \
      for (int mb = 0; mb < 4; ++mb) {                                        \
        const int row = mb * 16 + l15;                                        \
        bf16x8 bk = *(const bf16x8*)((const char*)Ks[cur] + row * 128 +       \
                                     ((ks * 64 + g * 16) ^ ((row & 7) << 4)));\
        s_acc[mb] = __builtin_amdgcn_mfma_f32_16x16x32_bf16(bk, aq[ks],       \
                                                            s_acc[mb], 0,0,0);\
      }                                                                       \
    }                                                                         \
    __builtin_amdgcn_s_setprio(0);                                            \
    /* softmax for row q=l15: in-lane 16 + 2 shfl */                          \
    float p[4][4];                                                            \
    float tmax = -1e30f;                                                      \
    _Pragma("unroll")                                                         \
    for (int mb = 0; mb < 4; ++mb)                                            \
      _Pragma("unroll")                                                       \
      for (int r = 0; r < 4; ++r) {                                           \
        p[mb][r] = s_acc[mb][r] * 0.125f + mv[mb][r];                         \
        tmax = fmaxf(tmax, p[mb][r]);                                         \
      }                                                                       \
    tmax = fmaxf(tmax, __shfl_xor(tmax, 16));                                 \
    tmax = fmaxf(tmax, __shfl_xor(tmax, 32));                                 \
    if (!__all(tmax - m_run <= 8.f)) {  /* T13 defer-max */                   \
      const float mnew = fmaxf(m_run, tmax);                                  \
      const float cf = __expf(m_run - mnew);                                  \
      m_run = mnew;                                                           \
      l_run *= cf;                                                            \
      float cfr[4];                                                           \
      _Pragma("unroll")                                                       \
      for (int r = 0; r < 4; ++r) cfr[r] = __shfl(cf, srcbase + r);           \
      _Pragma("unroll")                                                       \
      for (int db = 0; db < 4; ++db)                                          \
        _Pragma("unroll")                                                     \
        for (int r = 0; r < 4; ++r) o_acc[db][r] *= cfr[r];                   \
    }                                                                         \
    float psum = 0.f;                                                         \
    _Pragma("unroll")                                                         \
    for (int mb = 0; mb < 4; ++mb)                                            \
      _Pragma("unroll")                                                       \
      for (int r = 0; r < 4; ++r) {                                           \
        p[mb][r] = __expf(p[mb][r] - m_run);                                  \
        psum += p[mb][r];                                                     \
      }                                                                       \
    psum += __shfl_xor(psum, 16);                                             \
    psum += __shfl_xor(psum, 32);                                             \
    l_run += psum;                                                            \
    /* write P to LDS: row l15, 8B swizzled writes */                         \
    _Pragma("unroll")                                                         \
    for (int mb = 0; mb < 4; ++mb) {                                          \
      ushort4 pk;                                                             \
      pk.x = f2bf(p[mb][0]); pk.y = f2bf(p[mb][1]);                           \
      pk.z = f2bf(p[mb][2]); pk.w = f2bf(p[mb][3]);                           \
      *(ushort4*)((char*)pbase + l15 * 128 + ((mb * 32 + 8 * g) ^ pswz)) = pk;\
    }                                                                         \
    /* mask prefetch for t+2 into the SAME regs (issue-order pinned) */       \
    __builtin_amdgcn_sched_barrier(0);                                        \
    {                                                                         \
      const int tn = ((t) + 2 < NT) ? (t) + 2 : NT - 1;                       \
      const float* mnext = mrow + tn * 64;                                    \
      _Pragma("unroll")                                                       \
      for (int mb = 0; mb < 4; ++mb)                                          \
        mv[mb] = *(const f32x4*)(mnext + mb * 16 + 4 * g);                    \
    }                                                                         \
    /* same-wave P write->read ordering (per-wave region) */                  \
    asm volatile("s_waitcnt lgkmcnt(0)" ::: "memory");                        \
    __builtin_amdgcn_sched_barrier(0);                                        \
    /* O += P V */                                                            \
    __builtin_amdgcn_s_setprio(1);                                            \
    _Pragma("unroll")                                                         \
    for (int s = 0; s < 2; ++s) {                                             \
      bf16x8 pa = *(const bf16x8*)((const char*)pbase + l15 * 128 +           \
                                   ((s * 64 + 16 * g) ^ pswz));               \
      _Pragma("unroll")                                                       \
      for (int db = 0; db < 4; ++db) {                                        \
        const int row = db * 16 + l15;                                        \
        bf16x8 bv = *(const bf16x8*)((const char*)Vs[cur] + row * 128 +       \
                                     ((s * 64 + 16 * g) ^ ((row & 7) << 4))); \
        o_acc[db] = __builtin_amdgcn_mfma_f32_16x16x32_bf16(pa, bv,           \
                                                            o_acc[db], 0,0,0);\
      }                                                                       \
    }                                                                         \
    __builtin_amdgcn_s_setprio(0);                                            \
    /* counted barrier: K/V stage (2 loads) drained, 4 mask loads in flight */\
    asm volatile("s_waitcnt vmcnt(4)" ::: "memory");                          \
    __builtin_amdgcn_s_barrier();                                             \
    __builtin_amdgcn_sched_barrier(0);                                        \
  } while (0)

  for (int t = 0; t < NT; t += 2) {
    TILE_BODY(t, 0, mvA);
    TILE_BODY(t + 1, 1, mvB);
  }
#undef TILE_BODY
#undef STAGE

  // epilogue: redistribute l to o_acc rows, write Out[b][l][h][d] bf16
  const int b = bh >> 4, h = bh & 15;
  float lr[4];
#pragma unroll
  for (int r = 0; r < 4; ++r) lr[r] = __shfl(l_run, srcbase + r);
#pragma unroll
  for (int r = 0; r < 4; ++r) {
    const float inv = 1.f / lr[r];
    const int qg = q0 + 4 * g + r;
    u16* orow = Out + ((size_t)(b * LSEQ + qg) * NH + h) * HD;
#pragma unroll
    for (int db = 0; db < 4; ++db)
      orow[db * 16 + l15] = f2bf(o_acc[db][r] * inv);
  }
}

extern "C" void kernel_launch(void* const* d_in, const int* in_sizes, int n_in,
                              void* d_out, int out_size, void* d_ws, size_t ws_size,
                              hipStream_t stream) {
  (void)in_sizes; (void)n_in; (void)out_size; (void)ws_size;
  const float* q    = (const float*)d_in[0];
  const float* k    = (const float*)d_in[1];
  const float* v    = (const float*)d_in[2];
  const float* mask = (const float*)d_in[3];
  const float* Wq   = (const float*)d_in[4];
  const float* bq   = (const float*)d_in[5];
  const float* Wk   = (const float*)d_in[6];
  const float* bk   = (const float*)d_in[7];
  const float* Wv   = (const float*)d_in[8];
  const float* bv   = (const float*)d_in[9];
  const float* Wo   = (const float*)d_in[10];
  const float* bo   = (const float*)d_in[11];
  float* out = (float*)d_out;

  char* ws = (char*)d_ws;
  const size_t XB = (size_t)MTOK * HDIM * 2;  // 8 MiB (bf16 [4096][1024])
  const size_t WB = (size_t)HDIM * HDIM * 2;  // 2 MiB
  u16* xq   = (u16*)(ws);
  u16* xk   = (u16*)(ws + XB);
  u16* xv   = (u16*)(ws + 2 * XB);
  u16* WqT  = (u16*)(ws + 3 * XB);
  u16* WkT  = (u16*)(ws + 3 * XB + WB);
  u16* WvT  = (u16*)(ws + 3 * XB + 2 * WB);
  u16* WoT  = (u16*)(ws + 3 * XB + 3 * WB);
  u16* Qh   = (u16*)(ws + 3 * XB + 4 * WB);
  u16* Kh   = (u16*)(ws + 4 * XB + 4 * WB);
  u16* Vt   = (u16*)(ws + 5 * XB + 4 * WB);
  u16* aout = (u16*)(ws + 6 * XB + 4 * WB);

  // 1) converts (z=0..2) + weight transposes (z=3) in one launch
  prep_kernel<<<dim3((MTOK * HDIM) / 4 / 256, 1, 4), 256, 0, stream>>>(
      q, k, v, Wq, Wk, Wv, Wo, xq, xk, xv, WqT, WkT, WvT, WoT);
  // 2) projections (XCD-swizzled; plain direct epilogues - R12 config)
  proj_gemm_kernel<<<768, 256, 0, stream>>>(
      xq, xk, xv, WqT, WkT, WvT, bq, bk, bv, Qh, Kh, Vt);
  // 3) flash attention — LAUNCHED TWICE (idempotent) as a re-attribution probe:
  //    attn_dur = dur_us(this round) - 215.8
  attn_kernel<<<512, 512, 0, stream>>>(Qh, Kh, Vt, mask, aout);
  attn_kernel<<<512, 512, 0, stream>>>(Qh, Kh, Vt, mask, aout);
  // 4) output projection (128x64 tiles, 512 blocks = 2/CU)
  out_gemm_kernel<<<512, 256, 0, stream>>>(aout, WoT, bo, out);
}

// Round 16
// 251.640 us; speedup vs baseline: 1.3273x; 1.3273x over previous
//
#include <hip/hip_runtime.h>

// Problem constants (B=2, L=2048, H=1024, NH=16, HD=64)
#define NBATCH 2
#define LSEQ   2048
#define NH     16
#define HD     64
#define HDIM   1024
#define MTOK   4096   // NBATCH * LSEQ

typedef unsigned short u16;
typedef __attribute__((ext_vector_type(8))) short bf16x8;  // 8 bf16 (4 VGPRs)
typedef __attribute__((ext_vector_type(4))) float f32x4;

__device__ __forceinline__ u16 f2bf(float f) {
  union { float f; unsigned int u; } x; x.f = f;
  return (u16)((x.u + 0x7fffu + ((x.u >> 16) & 1u)) >> 16);  // RNE
}

__device__ __forceinline__ void gload_lds16(const void* g, void* l) {
  __builtin_amdgcn_global_load_lds(
      (const __attribute__((address_space(1))) unsigned int*)g,
      (__attribute__((address_space(3))) unsigned int*)l, 16, 0, 0);
}

// ---------------- prep: fp32->bf16 converts (z=0..2) + weight transposes (z=3) ----
__global__ void prep_kernel(
    const float* __restrict__ q, const float* __restrict__ k, const float* __restrict__ v,
    const float* __restrict__ W0, const float* __restrict__ W1,
    const float* __restrict__ W2, const float* __restrict__ W3,
    u16* __restrict__ xq, u16* __restrict__ xk, u16* __restrict__ xv,
    u16* __restrict__ T0, u16* __restrict__ T1, u16* __restrict__ T2,
    u16* __restrict__ T3) {
  __shared__ float tile[64][65];
  if (blockIdx.z < 3) {
    const float* in = (blockIdx.z == 0) ? q : (blockIdx.z == 1) ? k : v;
    u16* out = (blockIdx.z == 0) ? xq : (blockIdx.z == 1) ? xk : xv;
    int i = blockIdx.x * blockDim.x + threadIdx.x;  // 4096 blocks cover n/4
    float4 t4 = ((const float4*)in)[i];
    ushort4 o;
    o.x = f2bf(t4.x); o.y = f2bf(t4.y); o.z = f2bf(t4.z); o.w = f2bf(t4.w);
    ((ushort4*)out)[i] = o;
    return;
  }
  // z == 3: weight transpose+convert, 256 blocks per weight
  if (blockIdx.x >= 1024) return;
  const int sel = blockIdx.x >> 8, bx = blockIdx.x & 255;
  const float* W = (sel == 0) ? W0 : (sel == 1) ? W1 : (sel == 2) ? W2 : W3;
  u16* Wt = (sel == 0) ? T0 : (sel == 1) ? T1 : (sel == 2) ? T2 : T3;
  const int k0 = (bx & 15) << 6;
  const int n0 = (bx >> 4) << 6;
  const int t = threadIdx.x;
#pragma unroll
  for (int i = 0; i < 4; ++i) {
    int idx = t + i * 256;
    int r = idx >> 4, c = (idx & 15) << 2;
    float4 v4 = *(const float4*)&W[(size_t)(k0 + r) * HDIM + n0 + c];
    tile[r][c] = v4.x; tile[r][c + 1] = v4.y; tile[r][c + 2] = v4.z; tile[r][c + 3] = v4.w;
  }
  __syncthreads();
#pragma unroll
  for (int i = 0; i < 4; ++i) {
    int idx = t + i * 256;
    int r = idx >> 4, c = (idx & 15) << 2;  // r = n-local, c = k-local
    ushort4 o;
    o.x = f2bf(tile[c][r]);     o.y = f2bf(tile[c + 1][r]);
    o.z = f2bf(tile[c + 2][r]); o.w = f2bf(tile[c + 3][r]);
    *(ushort4*)&Wt[(size_t)(n0 + r) * HDIM + k0 + c] = o;
  }
}

// ---------------- GEMM core (proj): C[M,N] = A[M,K] * Bt[N,K]^T + bias --------
// 128x128 tile, BK=64, 4 waves (2x2), 16x16x32 bf16 MFMA. m97-style structure.
// MODE 0: write bf16 head-major Qh/Kh [B][NH][L][HD]
// MODE 2: write bf16 transposed Vt [B][NH][HD][L]
template <int MODE>
__device__ __forceinline__ void gemm_core(u16* As, u16* Bs, int m0, int n0,
    const u16* __restrict__ A, const u16* __restrict__ Bt,
    const float* __restrict__ bias, void* __restrict__ Cout) {
  const int tid = threadIdx.x;
  const int lane = tid & 63, wid = tid >> 6;
  const int l15 = lane & 15, g = lane >> 4;
  const int wr = wid >> 1, wc = wid & 1;
  f32x4 acc[4][4];
#pragma unroll
  for (int i = 0; i < 4; ++i)
#pragma unroll
    for (int j = 0; j < 4; ++j) acc[i][j] = (f32x4){0.f, 0.f, 0.f, 0.f};

  for (int t = 0; t < HDIM / 64; ++t) {
    const int k0 = t * 64;
    __syncthreads();  // previous tile fully consumed
#pragma unroll
    for (int i = 0; i < 4; ++i) {
      const int row = wid * 32 + i * 8 + (lane >> 3);
      const int colb = (lane & 7) * 16;
      gload_lds16((const char*)(A + (size_t)(m0 + row) * HDIM + k0) + colb,
                  (char*)As + (wid * 32 + i * 8) * 128);
      gload_lds16((const char*)(Bt + (size_t)(n0 + row) * HDIM + k0) + colb,
                  (char*)Bs + (wid * 32 + i * 8) * 128);
    }
    __syncthreads();  // staging visible (drains vmcnt)
#pragma unroll
    for (int ks = 0; ks < 2; ++ks) {
      bf16x8 a[4], b[4];
#pragma unroll
      for (int i = 0; i < 4; ++i) {
        const int row = wr * 64 + i * 16 + l15;
        a[i] = *(const bf16x8*)((const char*)As + row * 128 + ks * 64 + g * 16);
      }
#pragma unroll
      for (int j = 0; j < 4; ++j) {
        const int row = wc * 64 + j * 16 + l15;
        b[j] = *(const bf16x8*)((const char*)Bs + row * 128 + ks * 64 + g * 16);
      }
#pragma unroll
      for (int i = 0; i < 4; ++i)
#pragma unroll
        for (int j = 0; j < 4; ++j)
          acc[i][j] = __builtin_amdgcn_mfma_f32_16x16x32_bf16(a[i], b[j], acc[i][j], 0, 0, 0);
    }
  }
  // epilogue: C row = m0 + wr*64 + i*16 + 4*g + r ; col = n0 + wc*64 + j*16 + l15
#pragma unroll
  for (int i = 0; i < 4; ++i) {
    const int mrow = m0 + wr * 64 + i * 16 + 4 * g;
#pragma unroll
    for (int j = 0; j < 4; ++j) {
      const int ncol = n0 + wc * 64 + j * 16 + l15;
      const float bb = bias[ncol];
      if (MODE == 2) {
        const int bidx = mrow >> 11, l0 = mrow & (LSEQ - 1);
        const int h = ncol >> 6, d = ncol & 63;
        ushort4 o4;
        o4.x = f2bf(acc[i][j][0] + bb); o4.y = f2bf(acc[i][j][1] + bb);
        o4.z = f2bf(acc[i][j][2] + bb); o4.w = f2bf(acc[i][j][3] + bb);
        *(ushort4*)&((u16*)Cout)[(((size_t)bidx * NH + h) * HD + d) * LSEQ + l0] = o4;
      } else {
        const int h = ncol >> 6, d = ncol & 63;
        u16* o = (u16*)Cout;
#pragma unroll
        for (int r = 0; r < 4; ++r) {
          const int m = mrow + r;
          const int bidx = m >> 11, l = m & (LSEQ - 1);
          o[(((size_t)bidx * NH + h) * LSEQ + l) * HD + d] = f2bf(acc[i][j][r] + bb);
        }
      }
    }
  }
}

// proj: 1-D grid 768, XCD-bijective swizzle (nwg%8==0)
__global__ __launch_bounds__(256, 3) void proj_gemm_kernel(
    const u16* __restrict__ xq, const u16* __restrict__ xk, const u16* __restrict__ xv,
    const u16* __restrict__ WqT, const u16* __restrict__ WkT, const u16* __restrict__ WvT,
    const float* __restrict__ bq, const float* __restrict__ bk, const float* __restrict__ bv,
    u16* __restrict__ Qh, u16* __restrict__ Kh, u16* __restrict__ Vt) {
  __shared__ u16 As[128 * 64];
  __shared__ u16 Bs[128 * 64];
  const int h = blockIdx.x;
  const int l = (h & 7) * 96 + (h >> 3);  // XCD h&7 gets 96 consecutive tiles
  const int z = l >> 8, rem = l & 255;
  const int m0 = (rem >> 3) * 128, n0 = (rem & 7) * 128;
  if (z == 0)      gemm_core<0>(As, Bs, m0, n0, xq, WqT, bq, Qh);
  else if (z == 1) gemm_core<0>(As, Bs, m0, n0, xk, WkT, bk, Kh);
  else             gemm_core<2>(As, Bs, m0, n0, xv, WvT, bv, Vt);
}

// out: 128x64 tile, 512 blocks = 2/CU. 4 waves 2x2: wr rows 64, wc cols 32.
__global__ __launch_bounds__(256, 2) void out_gemm_kernel(
    const u16* __restrict__ A, const u16* __restrict__ WoT,
    const float* __restrict__ bo, float* __restrict__ out) {
  __shared__ u16 As[128 * 64];  // 16 KB
  __shared__ u16 Bs[64 * 64];   // 8 KB
  const int h = blockIdx.x;
  const int l = (h & 7) * 64 + (h >> 3);  // XCD-bijective (512 % 8 == 0)
  const int m0 = (l >> 4) * 128, n0 = (l & 15) * 64;
  const int lane = threadIdx.x & 63, wid = threadIdx.x >> 6;
  const int l15 = lane & 15, g = lane >> 4;
  const int wr = wid >> 1, wc = wid & 1;
  f32x4 acc[4][2];
#pragma unroll
  for (int i = 0; i < 4; ++i)
#pragma unroll
    for (int j = 0; j < 2; ++j) acc[i][j] = (f32x4){0.f, 0.f, 0.f, 0.f};

  for (int t = 0; t < HDIM / 64; ++t) {
    const int k0 = t * 64;
    __syncthreads();
    const int colb = (lane & 7) * 16;
#pragma unroll
    for (int i = 0; i < 4; ++i) {  // A: 32 rows per wave (128 total)
      const int row = wid * 32 + i * 8 + (lane >> 3);
      gload_lds16((const char*)(A + (size_t)(m0 + row) * HDIM + k0) + colb,
                  (char*)As + (wid * 32 + i * 8) * 128);
    }
#pragma unroll
    for (int i = 0; i < 2; ++i) {  // B: 16 rows per wave (64 total)
      const int row = wid * 16 + i * 8 + (lane >> 3);
      gload_lds16((const char*)(WoT + (size_t)(n0 + row) * HDIM + k0) + colb,
                  (char*)Bs + (wid * 16 + i * 8) * 128);
    }
    __syncthreads();
#pragma unroll
    for (int ks = 0; ks < 2; ++ks) {
      bf16x8 a[4], b[2];
#pragma unroll
      for (int i = 0; i < 4; ++i) {
        const int row = wr * 64 + i * 16 + l15;
        a[i] = *(const bf16x8*)((const char*)As + row * 128 + ks * 64 + g * 16);
      }
#pragma unroll
      for (int j = 0; j < 2; ++j) {
        const int row = wc * 32 + j * 16 + l15;
        b[j] = *(const bf16x8*)((const char*)Bs + row * 128 + ks * 64 + g * 16);
      }
#pragma unroll
      for (int i = 0; i < 4; ++i)
#pragma unroll
        for (int j = 0; j < 2; ++j)
          acc[i][j] = __builtin_amdgcn_mfma_f32_16x16x32_bf16(a[i], b[j], acc[i][j], 0, 0, 0);
    }
  }
#pragma unroll
  for (int i = 0; i < 4; ++i) {
    const int mrow = m0 + wr * 64 + i * 16 + 4 * g;
#pragma unroll
    for (int j = 0; j < 2; ++j) {
      const int ncol = n0 + wc * 32 + j * 16 + l15;
      const float bb = bo[ncol];
#pragma unroll
      for (int r = 0; r < 4; ++r)
        out[(size_t)(mrow + r) * HDIM + ncol] = acc[i][j][r] + bb;
    }
  }
}

// ---------------- flash attention (R12-best: QBLK=128, double-buffer, vmcnt(4)) ----
// 512 blocks x 512 threads (8 waves), each wave owns 16 q-rows. K/V tiles of 64
// double-buffered; each wave stages one 8-row slab of K and V (2 gload_lds/tile).
// bh-local XCD swizzle. Mask prefetched two tiles ahead in registers (mvA/mvB);
// end-of-tile barrier waits vmcnt(4) so mask loads stay in flight.
__global__ __launch_bounds__(512, 4) void attn_kernel(
    const u16* __restrict__ Qh, const u16* __restrict__ Kh,
    const u16* __restrict__ Vt, const float* __restrict__ mask,
    u16* __restrict__ Out /* [B][L][NH][HD] bf16 */) {
  __shared__ u16 Ks[2][64 * 64];   // 16 KB
  __shared__ u16 Vs[2][64 * 64];   // 16 KB
  __shared__ u16 Ps[8][16 * 64];   // 16 KB
  const int lane = threadIdx.x & 63, w = threadIdx.x >> 6;  // w in 0..7
  const int l15 = lane & 15, g = lane >> 4;
  // bh-locality swizzle: 512 blocks = 8 XCD x (4 heads x 16 q-blocks)
  const int kk = blockIdx.x >> 3, xcd = blockIdx.x & 7;
  const int bh = xcd * 4 + (kk >> 4);
  const int qb = kk & 15;
  const int q0 = qb * 128 + w * 16;
  const int NT = LSEQ / 64;

  // Q fragments: lane holds Q[q0 + l15][ks*32 + g*8 + j]
  bf16x8 aq[2];
  {
    const u16* qbase = Qh + ((size_t)bh * LSEQ + q0 + l15) * HD;
    aq[0] = *(const bf16x8*)(qbase + g * 8);
    aq[1] = *(const bf16x8*)(qbase + 32 + g * 8);
  }
  f32x4 o_acc[4];
#pragma unroll
  for (int db = 0; db < 4; ++db) o_acc[db] = (f32x4){0.f, 0.f, 0.f, 0.f};
  float m_run = -1e30f, l_run = 0.f;  // this lane's q-row = q0 + l15

  const size_t kbase = (size_t)bh * LSEQ * HD;   // Kh[bh][l][d]
  const size_t vbase = (size_t)bh * HD * LSEQ;   // Vt[bh][d][l]
  const int srow = w * 8 + (lane >> 3);          // this wave's staging row
  const int scolb = (lane & 7) * 16;

#define STAGE(buf, tt) do {                                                    \
    const int kv0_ = (tt) * 64;                                                \
    const int cb_ = scolb ^ ((srow & 7) << 4);                                 \
    gload_lds16((const char*)(Kh + kbase + (size_t)(kv0_ + srow) * HD) + cb_,  \
                (char*)Ks[buf] + (w * 8) * 128);                               \
    gload_lds16((const char*)(Vt + vbase + (size_t)srow * LSEQ + kv0_) + cb_,  \
                (char*)Vs[buf] + (w * 8) * 128);                               \
  } while (0)

  const float* mrow = mask + ((size_t)bh * LSEQ + q0 + l15) * LSEQ;
  f32x4 mvA[4], mvB[4];

  STAGE(0, 0);
#pragma unroll
  for (int mb = 0; mb < 4; ++mb) {  // mask tiles 0 and 1
    mvA[mb] = *(const f32x4*)(mrow + 0 * 64 + mb * 16 + 4 * g);
    mvB[mb] = *(const f32x4*)(mrow + 1 * 64 + mb * 16 + 4 * g);
  }
  __syncthreads();  // one-time full drain: tile 0 staged

  u16* pbase = Ps[w];
  const int srcbase = (lane & 48) | ((lane & 48) >> 2);  // lane g*16 + 4g (+r)
  const int pswz = (l15 & 7) << 4;

  // ---- one tile body; mv = this tile's mask regs (reloaded for t+2) ----
#define TILE_BODY(t, cur, mv) do {                                            \
    if ((t) + 1 < NT) STAGE((cur) ^ 1, (t) + 1);                              \
    /* S^T via mfma(K,Q): s_acc[mb][r] = S[q=l15][kv=mb*16+4g+r] */           \
    f32x4 s_acc[4];                                                           \
    _Pragma("unroll")                                                         \
    for (int mb = 0; mb < 4; ++mb) s_acc[mb] = (f32x4){0.f, 0.f, 0.f, 0.f};   \
    __builtin_amdgcn_s_setprio(1);                                            \
    _Pragma("unroll")                                                         \
    for (int ks = 0; ks < 2; ++ks) {                                          \
      _Pragma("unroll")                                                       \
      for (int mb = 0; mb < 4; ++mb) {                                        \
        const int row = mb * 16 + l15;                                        \
        bf16x8 bk = *(const bf16x8*)((const char*)Ks[cur] + row * 128 +       \
                                     ((ks * 64 + g * 16) ^ ((row & 7) << 4)));\
        s_acc[mb] = __builtin_amdgcn_mfma_f32_16x16x32_bf16(bk, aq[ks],       \
                                                            s_acc[mb], 0,0,0);\
      }                                                                       \
    }                                                                         \
    __builtin_amdgcn_s_setprio(0);                                            \
    /* softmax for row q=l15: in-lane 16 + 2 shfl */                          \
    float p[4][4];                                                            \
    float tmax = -1e30f;                                                      \
    _Pragma("unroll")                                                         \
    for (int mb = 0; mb < 4; ++mb)                                            \
      _Pragma("unroll")                                                       \
      for (int r = 0; r < 4; ++r) {                                           \
        p[mb][r] = s_acc[mb][r] * 0.125f + mv[mb][r];                         \
        tmax = fmaxf(tmax, p[mb][r]);                                         \
      }                                                                       \
    tmax = fmaxf(tmax, __shfl_xor(tmax, 16));                                 \
    tmax = fmaxf(tmax, __shfl_xor(tmax, 32));                                 \
    if (!__all(tmax - m_run <= 8.f)) {  /* T13 defer-max */                   \
      const float mnew = fmaxf(m_run, tmax);                                  \
      const float cf = __expf(m_run - mnew);                                  \
      m_run = mnew;                                                           \
      l_run *= cf;                                                            \
      float cfr[4];                                                           \
      _Pragma("unroll")                                                       \
      for (int r = 0; r < 4; ++r) cfr[r] = __shfl(cf, srcbase + r);           \
      _Pragma("unroll")                                                       \
      for (int db = 0; db < 4; ++db)                                          \
        _Pragma("unroll")                                                     \
        for (int r = 0; r < 4; ++r) o_acc[db][r] *= cfr[r];                   \
    }                                                                         \
    float psum = 0.f;                                                         \
    _Pragma("unroll")                                                         \
    for (int mb = 0; mb < 4; ++mb)                                            \
      _Pragma("unroll")                                                       \
      for (int r = 0; r < 4; ++r) {                                           \
        p[mb][r] = __expf(p[mb][r] - m_run);                                  \
        psum += p[mb][r];                                                     \
      }                                                                       \
    psum += __shfl_xor(psum, 16);                                             \
    psum += __shfl_xor(psum, 32);                                             \
    l_run += psum;                                                            \
    /* write P to LDS: row l15, 8B swizzled writes */                         \
    _Pragma("unroll")                                                         \
    for (int mb = 0; mb < 4; ++mb) {                                          \
      ushort4 pk;                                                             \
      pk.x = f2bf(p[mb][0]); pk.y = f2bf(p[mb][1]);                           \
      pk.z = f2bf(p[mb][2]); pk.w = f2bf(p[mb][3]);                           \
      *(ushort4*)((char*)pbase + l15 * 128 + ((mb * 32 + 8 * g) ^ pswz)) = pk;\
    }                                                                         \
    /* mask prefetch for t+2 into the SAME regs (issue-order pinned) */       \
    __builtin_amdgcn_sched_barrier(0);                                        \
    {                                                                         \
      const int tn = ((t) + 2 < NT) ? (t) + 2 : NT - 1;                       \
      const float* mnext = mrow + tn * 64;                                    \
      _Pragma("unroll")                                                       \
      for (int mb = 0; mb < 4; ++mb)                                          \
        mv[mb] = *(const f32x4*)(mnext + mb * 16 + 4 * g);                    \
    }                                                                         \
    /* same-wave P write->read ordering (per-wave region) */                  \
    asm volatile("s_waitcnt lgkmcnt(0)" ::: "memory");                        \
    __builtin_amdgcn_sched_barrier(0);                                        \
    /* O += P V */                                                            \
    __builtin_amdgcn_s_setprio(1);                                            \
    _Pragma("unroll")                                                         \
    for (int s = 0; s < 2; ++s) {                                             \
      bf16x8 pa = *(const bf16x8*)((const char*)pbase + l15 * 128 +           \
                                   ((s * 64 + 16 * g) ^ pswz));               \
      _Pragma("unroll")                                                       \
      for (int db = 0; db < 4; ++db) {                                        \
        const int row = db * 16 + l15;                                        \
        bf16x8 bv = *(const bf16x8*)((const char*)Vs[cur] + row * 128 +       \
                                     ((s * 64 + 16 * g) ^ ((row & 7) << 4))); \
        o_acc[db] = __builtin_amdgcn_mfma_f32_16x16x32_bf16(pa, bv,           \
                                                            o_acc[db], 0,0,0);\
      }                                                                       \
    }                                                                         \
    __builtin_amdgcn_s_setprio(0);                                            \
    /* counted barrier: K/V stage (2 loads) drained, 4 mask loads in flight */\
    asm volatile("s_waitcnt vmcnt(4)" ::: "memory");                          \
    __builtin_amdgcn_s_barrier();                                             \
    __builtin_amdgcn_sched_barrier(0);                                        \
  } while (0)

  for (int t = 0; t < NT; t += 2) {
    TILE_BODY(t, 0, mvA);
    TILE_BODY(t + 1, 1, mvB);
  }
#undef TILE_BODY
#undef STAGE

  // epilogue: redistribute l to o_acc rows, write Out[b][l][h][d] bf16
  const int b = bh >> 4, h = bh & 15;
  float lr[4];
#pragma unroll
  for (int r = 0; r < 4; ++r) lr[r] = __shfl(l_run, srcbase + r);
#pragma unroll
  for (int r = 0; r < 4; ++r) {
    const float inv = 1.f / lr[r];
    const int qg = q0 + 4 * g + r;
    u16* orow = Out + ((size_t)(b * LSEQ + qg) * NH + h) * HD;
#pragma unroll
    for (int db = 0; db < 4; ++db)
      orow[db * 16 + l15] = f2bf(o_acc[db][r] * inv);
  }
}

extern "C" void kernel_launch(void* const* d_in, const int* in_sizes, int n_in,
                              void* d_out, int out_size, void* d_ws, size_t ws_size,
                              hipStream_t stream) {
  (void)in_sizes; (void)n_in; (void)out_size; (void)ws_size;
  const float* q    = (const float*)d_in[0];
  const float* k    = (const float*)d_in[1];
  const float* v    = (const float*)d_in[2];
  const float* mask = (const float*)d_in[3];
  const float* Wq   = (const float*)d_in[4];
  const float* bq   = (const float*)d_in[5];
  const float* Wk   = (const float*)d_in[6];
  const float* bk   = (const float*)d_in[7];
  const float* Wv   = (const float*)d_in[8];
  const float* bv   = (const float*)d_in[9];
  const float* Wo   = (const float*)d_in[10];
  const float* bo   = (const float*)d_in[11];
  float* out = (float*)d_out;

  char* ws = (char*)d_ws;
  const size_t XB = (size_t)MTOK * HDIM * 2;  // 8 MiB (bf16 [4096][1024])
  const size_t WB = (size_t)HDIM * HDIM * 2;  // 2 MiB
  u16* xq   = (u16*)(ws);
  u16* xk   = (u16*)(ws + XB);
  u16* xv   = (u16*)(ws + 2 * XB);
  u16* WqT  = (u16*)(ws + 3 * XB);
  u16* WkT  = (u16*)(ws + 3 * XB + WB);
  u16* WvT  = (u16*)(ws + 3 * XB + 2 * WB);
  u16* WoT  = (u16*)(ws + 3 * XB + 3 * WB);
  u16* Qh   = (u16*)(ws + 3 * XB + 4 * WB);
  u16* Kh   = (u16*)(ws + 4 * XB + 4 * WB);
  u16* Vt   = (u16*)(ws + 5 * XB + 4 * WB);
  u16* aout = (u16*)(ws + 6 * XB + 4 * WB);

  // 1) converts (z=0..2) + weight transposes (z=3) in one launch
  prep_kernel<<<dim3((MTOK * HDIM) / 4 / 256, 1, 4), 256, 0, stream>>>(
      q, k, v, Wq, Wk, Wv, Wo, xq, xk, xv, WqT, WkT, WvT, WoT);
  // 2) projections — LAUNCHED TWICE (idempotent) as an attribution probe:
  //    proj_dur = dur_us(this round) - 215.8
  proj_gemm_kernel<<<768, 256, 0, stream>>>(
      xq, xk, xv, WqT, WkT, WvT, bq, bk, bv, Qh, Kh, Vt);
  proj_gemm_kernel<<<768, 256, 0, stream>>>(
      xq, xk, xv, WqT, WkT, WvT, bq, bk, bv, Qh, Kh, Vt);
  // 3) flash attention (R12-best config, single launch)
  attn_kernel<<<512, 512, 0, stream>>>(Qh, Kh, Vt, mask, aout);
  // 4) output projection (128x64 tiles, 512 blocks = 2/CU)
  out_gemm_kernel<<<512, 256, 0, stream>>>(aout, WoT, bo, out);
}

// Round 17
// 215.531 us; speedup vs baseline: 1.5497x; 1.1675x over previous
//
#include <hip/hip_runtime.h>

// Problem constants (B=2, L=2048, H=1024, NH=16, HD=64)
#define NBATCH 2
#define LSEQ   2048
#define NH     16
#define HD     64
#define HDIM   1024
#define MTOK   4096   // NBATCH * LSEQ

typedef unsigned short u16;
typedef __attribute__((ext_vector_type(8))) short bf16x8;  // 8 bf16 (4 VGPRs)
typedef __attribute__((ext_vector_type(4))) float f32x4;

__device__ __forceinline__ u16 f2bf(float f) {
  union { float f; unsigned int u; } x; x.f = f;
  return (u16)((x.u + 0x7fffu + ((x.u >> 16) & 1u)) >> 16);  // RNE
}

__device__ __forceinline__ void gload_lds16(const void* g, void* l) {
  __builtin_amdgcn_global_load_lds(
      (const __attribute__((address_space(1))) unsigned int*)g,
      (__attribute__((address_space(3))) unsigned int*)l, 16, 0, 0);
}

// ---------------- prep: fp32->bf16 converts (z=0..2) + weight transposes (z=3) ----
__global__ void prep_kernel(
    const float* __restrict__ q, const float* __restrict__ k, const float* __restrict__ v,
    const float* __restrict__ W0, const float* __restrict__ W1,
    const float* __restrict__ W2, const float* __restrict__ W3,
    u16* __restrict__ xq, u16* __restrict__ xk, u16* __restrict__ xv,
    u16* __restrict__ T0, u16* __restrict__ T1, u16* __restrict__ T2,
    u16* __restrict__ T3) {
  __shared__ float tile[64][65];
  if (blockIdx.z < 3) {
    const float* in = (blockIdx.z == 0) ? q : (blockIdx.z == 1) ? k : v;
    u16* out = (blockIdx.z == 0) ? xq : (blockIdx.z == 1) ? xk : xv;
    int i = blockIdx.x * blockDim.x + threadIdx.x;  // 4096 blocks cover n/4
    float4 t4 = ((const float4*)in)[i];
    ushort4 o;
    o.x = f2bf(t4.x); o.y = f2bf(t4.y); o.z = f2bf(t4.z); o.w = f2bf(t4.w);
    ((ushort4*)out)[i] = o;
    return;
  }
  // z == 3: weight transpose+convert, 256 blocks per weight
  if (blockIdx.x >= 1024) return;
  const int sel = blockIdx.x >> 8, bx = blockIdx.x & 255;
  const float* W = (sel == 0) ? W0 : (sel == 1) ? W1 : (sel == 2) ? W2 : W3;
  u16* Wt = (sel == 0) ? T0 : (sel == 1) ? T1 : (sel == 2) ? T2 : T3;
  const int k0 = (bx & 15) << 6;
  const int n0 = (bx >> 4) << 6;
  const int t = threadIdx.x;
#pragma unroll
  for (int i = 0; i < 4; ++i) {
    int idx = t + i * 256;
    int r = idx >> 4, c = (idx & 15) << 2;
    float4 v4 = *(const float4*)&W[(size_t)(k0 + r) * HDIM + n0 + c];
    tile[r][c] = v4.x; tile[r][c + 1] = v4.y; tile[r][c + 2] = v4.z; tile[r][c + 3] = v4.w;
  }
  __syncthreads();
#pragma unroll
  for (int i = 0; i < 4; ++i) {
    int idx = t + i * 256;
    int r = idx >> 4, c = (idx & 15) << 2;  // r = n-local, c = k-local
    ushort4 o;
    o.x = f2bf(tile[c][r]);     o.y = f2bf(tile[c + 1][r]);
    o.z = f2bf(tile[c + 2][r]); o.w = f2bf(tile[c + 3][r]);
    *(ushort4*)&Wt[(size_t)(n0 + r) * HDIM + k0 + c] = o;
  }
}

// ---------------- GEMM core (proj): C[M,N] = A[M,K] * Bt[N,K]^T + bias --------
// 128x128 tile, BK=64, 4 waves (2x2), 16x16x32 bf16 MFMA. m97-style structure.
// MODE 0: write bf16 head-major Qh/Kh [B][NH][L][HD]
// MODE 2: write bf16 transposed Vt [B][NH][HD][L]
template <int MODE>
__device__ __forceinline__ void gemm_core(u16* As, u16* Bs, int m0, int n0,
    const u16* __restrict__ A, const u16* __restrict__ Bt,
    const float* __restrict__ bias, void* __restrict__ Cout) {
  const int tid = threadIdx.x;
  const int lane = tid & 63, wid = tid >> 6;
  const int l15 = lane & 15, g = lane >> 4;
  const int wr = wid >> 1, wc = wid & 1;
  f32x4 acc[4][4];
#pragma unroll
  for (int i = 0; i < 4; ++i)
#pragma unroll
    for (int j = 0; j < 4; ++j) acc[i][j] = (f32x4){0.f, 0.f, 0.f, 0.f};

  for (int t = 0; t < HDIM / 64; ++t) {
    const int k0 = t * 64;
    __syncthreads();  // previous tile fully consumed
#pragma unroll
    for (int i = 0; i < 4; ++i) {
      const int row = wid * 32 + i * 8 + (lane >> 3);
      const int colb = (lane & 7) * 16;
      gload_lds16((const char*)(A + (size_t)(m0 + row) * HDIM + k0) + colb,
                  (char*)As + (wid * 32 + i * 8) * 128);
      gload_lds16((const char*)(Bt + (size_t)(n0 + row) * HDIM + k0) + colb,
                  (char*)Bs + (wid * 32 + i * 8) * 128);
    }
    __syncthreads();  // staging visible (drains vmcnt)
#pragma unroll
    for (int ks = 0; ks < 2; ++ks) {
      bf16x8 a[4], b[4];
#pragma unroll
      for (int i = 0; i < 4; ++i) {
        const int row = wr * 64 + i * 16 + l15;
        a[i] = *(const bf16x8*)((const char*)As + row * 128 + ks * 64 + g * 16);
      }
#pragma unroll
      for (int j = 0; j < 4; ++j) {
        const int row = wc * 64 + j * 16 + l15;
        b[j] = *(const bf16x8*)((const char*)Bs + row * 128 + ks * 64 + g * 16);
      }
#pragma unroll
      for (int i = 0; i < 4; ++i)
#pragma unroll
        for (int j = 0; j < 4; ++j)
          acc[i][j] = __builtin_amdgcn_mfma_f32_16x16x32_bf16(a[i], b[j], acc[i][j], 0, 0, 0);
    }
  }
  // epilogue: C row = m0 + wr*64 + i*16 + 4*g + r ; col = n0 + wc*64 + j*16 + l15
#pragma unroll
  for (int i = 0; i < 4; ++i) {
    const int mrow = m0 + wr * 64 + i * 16 + 4 * g;
#pragma unroll
    for (int j = 0; j < 4; ++j) {
      const int ncol = n0 + wc * 64 + j * 16 + l15;
      const float bb = bias[ncol];
      if (MODE == 2) {
        const int bidx = mrow >> 11, l0 = mrow & (LSEQ - 1);
        const int h = ncol >> 6, d = ncol & 63;
        ushort4 o4;
        o4.x = f2bf(acc[i][j][0] + bb); o4.y = f2bf(acc[i][j][1] + bb);
        o4.z = f2bf(acc[i][j][2] + bb); o4.w = f2bf(acc[i][j][3] + bb);
        *(ushort4*)&((u16*)Cout)[(((size_t)bidx * NH + h) * HD + d) * LSEQ + l0] = o4;
      } else {
        const int h = ncol >> 6, d = ncol & 63;
        u16* o = (u16*)Cout;
#pragma unroll
        for (int r = 0; r < 4; ++r) {
          const int m = mrow + r;
          const int bidx = m >> 11, l = m & (LSEQ - 1);
          o[(((size_t)bidx * NH + h) * LSEQ + l) * HD + d] = f2bf(acc[i][j][r] + bb);
        }
      }
    }
  }
}

// proj: 1-D grid 768, XCD-bijective swizzle (nwg%8==0)
__global__ __launch_bounds__(256, 3) void proj_gemm_kernel(
    const u16* __restrict__ xq, const u16* __restrict__ xk, const u16* __restrict__ xv,
    const u16* __restrict__ WqT, const u16* __restrict__ WkT, const u16* __restrict__ WvT,
    const float* __restrict__ bq, const float* __restrict__ bk, const float* __restrict__ bv,
    u16* __restrict__ Qh, u16* __restrict__ Kh, u16* __restrict__ Vt) {
  __shared__ u16 As[128 * 64];
  __shared__ u16 Bs[128 * 64];
  const int h = blockIdx.x;
  const int l = (h & 7) * 96 + (h >> 3);  // XCD h&7 gets 96 consecutive tiles
  const int z = l >> 8, rem = l & 255;
  const int m0 = (rem >> 3) * 128, n0 = (rem & 7) * 128;
  if (z == 0)      gemm_core<0>(As, Bs, m0, n0, xq, WqT, bq, Qh);
  else if (z == 1) gemm_core<0>(As, Bs, m0, n0, xk, WkT, bk, Kh);
  else             gemm_core<2>(As, Bs, m0, n0, xv, WvT, bv, Vt);
}

// out: 128x64 tile, 512 blocks. 4 waves 2x2: wr rows 64, wc cols 32.
// (256,3): 3 blocks/CU where the allocator permits (24KB LDS allows 6).
__global__ __launch_bounds__(256, 3) void out_gemm_kernel(
    const u16* __restrict__ A, const u16* __restrict__ WoT,
    const float* __restrict__ bo, float* __restrict__ out) {
  __shared__ u16 As[128 * 64];  // 16 KB
  __shared__ u16 Bs[64 * 64];   // 8 KB
  const int h = blockIdx.x;
  const int l = (h & 7) * 64 + (h >> 3);  // XCD-bijective (512 % 8 == 0)
  const int m0 = (l >> 4) * 128, n0 = (l & 15) * 64;
  const int lane = threadIdx.x & 63, wid = threadIdx.x >> 6;
  const int l15 = lane & 15, g = lane >> 4;
  const int wr = wid >> 1, wc = wid & 1;
  f32x4 acc[4][2];
#pragma unroll
  for (int i = 0; i < 4; ++i)
#pragma unroll
    for (int j = 0; j < 2; ++j) acc[i][j] = (f32x4){0.f, 0.f, 0.f, 0.f};

  for (int t = 0; t < HDIM / 64; ++t) {
    const int k0 = t * 64;
    __syncthreads();
    const int colb = (lane & 7) * 16;
#pragma unroll
    for (int i = 0; i < 4; ++i) {  // A: 32 rows per wave (128 total)
      const int row = wid * 32 + i * 8 + (lane >> 3);
      gload_lds16((const char*)(A + (size_t)(m0 + row) * HDIM + k0) + colb,
                  (char*)As + (wid * 32 + i * 8) * 128);
    }
#pragma unroll
    for (int i = 0; i < 2; ++i) {  // B: 16 rows per wave (64 total)
      const int row = wid * 16 + i * 8 + (lane >> 3);
      gload_lds16((const char*)(WoT + (size_t)(n0 + row) * HDIM + k0) + colb,
                  (char*)Bs + (wid * 16 + i * 8) * 128);
    }
    __syncthreads();
#pragma unroll
    for (int ks = 0; ks < 2; ++ks) {
      bf16x8 a[4], b[2];
#pragma unroll
      for (int i = 0; i < 4; ++i) {
        const int row = wr * 64 + i * 16 + l15;
        a[i] = *(const bf16x8*)((const char*)As + row * 128 + ks * 64 + g * 16);
      }
#pragma unroll
      for (int j = 0; j < 2; ++j) {
        const int row = wc * 32 + j * 16 + l15;
        b[j] = *(const bf16x8*)((const char*)Bs + row * 128 + ks * 64 + g * 16);
      }
#pragma unroll
      for (int i = 0; i < 4; ++i)
#pragma unroll
        for (int j = 0; j < 2; ++j)
          acc[i][j] = __builtin_amdgcn_mfma_f32_16x16x32_bf16(a[i], b[j], acc[i][j], 0, 0, 0);
    }
  }
#pragma unroll
  for (int i = 0; i < 4; ++i) {
    const int mrow = m0 + wr * 64 + i * 16 + 4 * g;
#pragma unroll
    for (int j = 0; j < 2; ++j) {
      const int ncol = n0 + wc * 32 + j * 16 + l15;
      const float bb = bo[ncol];
#pragma unroll
      for (int r = 0; r < 4; ++r)
        out[(size_t)(mrow + r) * HDIM + ncol] = acc[i][j][r] + bb;
    }
  }
}

// ---------------- flash attention (R12-best: QBLK=128, double-buffer, vmcnt(4)) ----
// 512 blocks x 512 threads (8 waves), each wave owns 16 q-rows. K/V tiles of 64
// double-buffered; each wave stages one 8-row slab of K and V (2 gload_lds/tile).
// bh-local XCD swizzle. Mask prefetched two tiles ahead in registers (mvA/mvB);
// end-of-tile barrier waits vmcnt(4) so mask loads stay in flight.
__global__ __launch_bounds__(512, 4) void attn_kernel(
    const u16* __restrict__ Qh, const u16* __restrict__ Kh,
    const u16* __restrict__ Vt, const float* __restrict__ mask,
    u16* __restrict__ Out /* [B][L][NH][HD] bf16 */) {
  __shared__ u16 Ks[2][64 * 64];   // 16 KB
  __shared__ u16 Vs[2][64 * 64];   // 16 KB
  __shared__ u16 Ps[8][16 * 64];   // 16 KB
  const int lane = threadIdx.x & 63, w = threadIdx.x >> 6;  // w in 0..7
  const int l15 = lane & 15, g = lane >> 4;
  // bh-locality swizzle: 512 blocks = 8 XCD x (4 heads x 16 q-blocks)
  const int kk = blockIdx.x >> 3, xcd = blockIdx.x & 7;
  const int bh = xcd * 4 + (kk >> 4);
  const int qb = kk & 15;
  const int q0 = qb * 128 + w * 16;
  const int NT = LSEQ / 64;

  // Q fragments: lane holds Q[q0 + l15][ks*32 + g*8 + j]
  bf16x8 aq[2];
  {
    const u16* qbase = Qh + ((size_t)bh * LSEQ + q0 + l15) * HD;
    aq[0] = *(const bf16x8*)(qbase + g * 8);
    aq[1] = *(const bf16x8*)(qbase + 32 + g * 8);
  }
  f32x4 o_acc[4];
#pragma unroll
  for (int db = 0; db < 4; ++db) o_acc[db] = (f32x4){0.f, 0.f, 0.f, 0.f};
  float m_run = -1e30f, l_run = 0.f;  // this lane's q-row = q0 + l15

  const size_t kbase = (size_t)bh * LSEQ * HD;   // Kh[bh][l][d]
  const size_t vbase = (size_t)bh * HD * LSEQ;   // Vt[bh][d][l]
  const int srow = w * 8 + (lane >> 3);          // this wave's staging row
  const int scolb = (lane & 7) * 16;

#define STAGE(buf, tt) do {                                                    \
    const int kv0_ = (tt) * 64;                                                \
    const int cb_ = scolb ^ ((srow & 7) << 4);                                 \
    gload_lds16((const char*)(Kh + kbase + (size_t)(kv0_ + srow) * HD) + cb_,  \
                (char*)Ks[buf] + (w * 8) * 128);                               \
    gload_lds16((const char*)(Vt + vbase + (size_t)srow * LSEQ + kv0_) + cb_,  \
                (char*)Vs[buf] + (w * 8) * 128);                               \
  } while (0)

  const float* mrow = mask + ((size_t)bh * LSEQ + q0 + l15) * LSEQ;
  f32x4 mvA[4], mvB[4];

  STAGE(0, 0);
#pragma unroll
  for (int mb = 0; mb < 4; ++mb) {  // mask tiles 0 and 1
    mvA[mb] = *(const f32x4*)(mrow + 0 * 64 + mb * 16 + 4 * g);
    mvB[mb] = *(const f32x4*)(mrow + 1 * 64 + mb * 16 + 4 * g);
  }
  __syncthreads();  // one-time full drain: tile 0 staged

  u16* pbase = Ps[w];
  const int srcbase = (lane & 48) | ((lane & 48) >> 2);  // lane g*16 + 4g (+r)
  const int pswz = (l15 & 7) << 4;

  // ---- one tile body; mv = this tile's mask regs (reloaded for t+2) ----
#define TILE_BODY(t, cur, mv) do {                                            \
    if ((t) + 1 < NT) STAGE((cur) ^ 1, (t) + 1);                              \
    /* S^T via mfma(K,Q): s_acc[mb][r] = S[q=l15][kv=mb*16+4g+r] */           \
    f32x4 s_acc[4];                                                           \
    _Pragma("unroll")                                                         \
    for (int mb = 0; mb < 4; ++mb) s_acc[mb] = (f32x4){0.f, 0.f, 0.f, 0.f};   \
    __builtin_amdgcn_s_setprio(1);                                            \
    _Pragma("unroll")                                                         \
    for (int ks = 0; ks < 2; ++ks) {                                          \
      _Pragma("unroll")                                                       \
      for (int mb = 0; mb < 4; ++mb) {                                        \
        const int row = mb * 16 + l15;                                        \
        bf16x8 bk = *(const bf16x8*)((const char*)Ks[cur] + row * 128 +       \
                                     ((ks * 64 + g * 16) ^ ((row & 7) << 4)));\
        s_acc[mb] = __builtin_amdgcn_mfma_f32_16x16x32_bf16(bk, aq[ks],       \
                                                            s_acc[mb], 0,0,0);\
      }                                                                       \
    }                                                                         \
    __builtin_amdgcn_s_setprio(0);                                            \
    /* softmax for row q=l15: in-lane 16 + 2 shfl */                          \
    float p[4][4];                                                            \
    float tmax = -1e30f;                                                      \
    _Pragma("unroll")                                                         \
    for (int mb = 0; mb < 4; ++mb)                                            \
      _Pragma("unroll")                                                       \
      for (int r = 0; r < 4; ++r) {                                           \
        p[mb][r] = s_acc[mb][r] * 0.125f + mv[mb][r];                         \
        tmax = fmaxf(tmax, p[mb][r]);                                         \
      }                                                                       \
    tmax = fmaxf(tmax, __shfl_xor(tmax, 16));                                 \
    tmax = fmaxf(tmax, __shfl_xor(tmax, 32));                                 \
    if (!__all(tmax - m_run <= 8.f)) {  /* T13 defer-max */                   \
      const float mnew = fmaxf(m_run, tmax);                                  \
      const float cf = __expf(m_run - mnew);                                  \
      m_run = mnew;                                                           \
      l_run *= cf;                                                            \
      float cfr[4];                                                           \
      _Pragma("unroll")                                                       \
      for (int r = 0; r < 4; ++r) cfr[r] = __shfl(cf, srcbase + r);           \
      _Pragma("unroll")                                                       \
      for (int db = 0; db < 4; ++db)                                          \
        _Pragma("unroll")                                                     \
        for (int r = 0; r < 4; ++r) o_acc[db][r] *= cfr[r];                   \
    }                                                                         \
    float psum = 0.f;                                                         \
    _Pragma("unroll")                                                         \
    for (int mb = 0; mb < 4; ++mb)                                            \
      _Pragma("unroll")                                                       \
      for (int r = 0; r < 4; ++r) {                                           \
        p[mb][r] = __expf(p[mb][r] - m_run);                                  \
        psum += p[mb][r];                                                     \
      }                                                                       \
    psum += __shfl_xor(psum, 16);                                             \
    psum += __shfl_xor(psum, 32);                                             \
    l_run += psum;                                                            \
    /* write P to LDS: row l15, 8B swizzled writes */                         \
    _Pragma("unroll")                                                         \
    for (int mb = 0; mb < 4; ++mb) {                                          \
      ushort4 pk;                                                             \
      pk.x = f2bf(p[mb][0]); pk.y = f2bf(p[mb][1]);                           \
      pk.z = f2bf(p[mb][2]); pk.w = f2bf(p[mb][3]);                           \
      *(ushort4*)((char*)pbase + l15 * 128 + ((mb * 32 + 8 * g) ^ pswz)) = pk;\
    }                                                                         \
    /* mask prefetch for t+2 into the SAME regs (issue-order pinned) */       \
    __builtin_amdgcn_sched_barrier(0);                                        \
    {                                                                         \
      const int tn = ((t) + 2 < NT) ? (t) + 2 : NT - 1;                       \
      const float* mnext = mrow + tn * 64;                                    \
      _Pragma("unroll")                                                       \
      for (int mb = 0; mb < 4; ++mb)                                          \
        mv[mb] = *(const f32x4*)(mnext + mb * 16 + 4 * g);                    \
    }                                                                         \
    /* same-wave P write->read ordering (per-wave region) */                  \
    asm volatile("s_waitcnt lgkmcnt(0)" ::: "memory");                        \
    __builtin_amdgcn_sched_barrier(0);                                        \
    /* O += P V */                                                            \
    __builtin_amdgcn_s_setprio(1);                                            \
    _Pragma("unroll")                                                         \
    for (int s = 0; s < 2; ++s) {                                             \
      bf16x8 pa = *(const bf16x8*)((const char*)pbase + l15 * 128 +           \
                                   ((s * 64 + 16 * g) ^ pswz));               \
      _Pragma("unroll")                                                       \
      for (int db = 0; db < 4; ++db) {                                        \
        const int row = db * 16 + l15;                                        \
        bf16x8 bv = *(const bf16x8*)((const char*)Vs[cur] + row * 128 +       \
                                     ((s * 64 + 16 * g) ^ ((row & 7) << 4))); \
        o_acc[db] = __builtin_amdgcn_mfma_f32_16x16x32_bf16(pa, bv,           \
                                                            o_acc[db], 0,0,0);\
      }                                                                       \
    }                                                                         \
    __builtin_amdgcn_s_setprio(0);                                            \
    /* counted barrier: K/V stage (2 loads) drained, 4 mask loads in flight */\
    asm volatile("s_waitcnt vmcnt(4)" ::: "memory");                          \
    __builtin_amdgcn_s_barrier();                                             \
    __builtin_amdgcn_sched_barrier(0);                                        \
  } while (0)

  for (int t = 0; t < NT; t += 2) {
    TILE_BODY(t, 0, mvA);
    TILE_BODY(t + 1, 1, mvB);
  }
#undef TILE_BODY
#undef STAGE

  // epilogue: redistribute l to o_acc rows, write Out[b][l][h][d] bf16
  const int b = bh >> 4, h = bh & 15;
  float lr[4];
#pragma unroll
  for (int r = 0; r < 4; ++r) lr[r] = __shfl(l_run, srcbase + r);
#pragma unroll
  for (int r = 0; r < 4; ++r) {
    const float inv = 1.f / lr[r];
    const int qg = q0 + 4 * g + r;
    u16* orow = Out + ((size_t)(b * LSEQ + qg) * NH + h) * HD;
#pragma unroll
    for (int db = 0; db < 4; ++db)
      orow[db * 16 + l15] = f2bf(o_acc[db][r] * inv);
  }
}

extern "C" void kernel_launch(void* const* d_in, const int* in_sizes, int n_in,
                              void* d_out, int out_size, void* d_ws, size_t ws_size,
                              hipStream_t stream) {
  (void)in_sizes; (void)n_in; (void)out_size; (void)ws_size;
  const float* q    = (const float*)d_in[0];
  const float* k    = (const float*)d_in[1];
  const float* v    = (const float*)d_in[2];
  const float* mask = (const float*)d_in[3];
  const float* Wq   = (const float*)d_in[4];
  const float* bq   = (const float*)d_in[5];
  const float* Wk   = (const float*)d_in[6];
  const float* bk   = (const float*)d_in[7];
  const float* Wv   = (const float*)d_in[8];
  const float* bv   = (const float*)d_in[9];
  const float* Wo   = (const float*)d_in[10];
  const float* bo   = (const float*)d_in[11];
  float* out = (float*)d_out;

  char* ws = (char*)d_ws;
  const size_t XB = (size_t)MTOK * HDIM * 2;  // 8 MiB (bf16 [4096][1024])
  const size_t WB = (size_t)HDIM * HDIM * 2;  // 2 MiB
  u16* xq   = (u16*)(ws);
  u16* xk   = (u16*)(ws + XB);
  u16* xv   = (u16*)(ws + 2 * XB);
  u16* WqT  = (u16*)(ws + 3 * XB);
  u16* WkT  = (u16*)(ws + 3 * XB + WB);
  u16* WvT  = (u16*)(ws + 3 * XB + 2 * WB);
  u16* WoT  = (u16*)(ws + 3 * XB + 3 * WB);
  u16* Qh   = (u16*)(ws + 3 * XB + 4 * WB);
  u16* Kh   = (u16*)(ws + 4 * XB + 4 * WB);
  u16* Vt   = (u16*)(ws + 5 * XB + 4 * WB);
  u16* aout = (u16*)(ws + 6 * XB + 4 * WB);

  // 1) converts (z=0..2) + weight transposes (z=3) in one launch
  prep_kernel<<<dim3((MTOK * HDIM) / 4 / 256, 1, 4), 256, 0, stream>>>(
      q, k, v, Wq, Wk, Wv, Wo, xq, xk, xv, WqT, WkT, WvT, WoT);
  // 2) projections (XCD-swizzled; plain direct epilogues)
  proj_gemm_kernel<<<768, 256, 0, stream>>>(
      xq, xk, xv, WqT, WkT, WvT, bq, bk, bv, Qh, Kh, Vt);
  // 3) flash attention (R12-best config)
  attn_kernel<<<512, 512, 0, stream>>>(Qh, Kh, Vt, mask, aout);
  // 4) output projection (128x64 tiles, 512 blocks)
  out_gemm_kernel<<<512, 256, 0, stream>>>(aout, WoT, bo, out);
}